// Round 7
// baseline (1279.071 us; speedup 1.0000x reference)
//
#include <hip/hip_runtime.h>
#include <hip/hip_bf16.h>

// Model dims (compile-time)
#define BB 128
#define SS 256
#define DD 128
#define DI 256      // 2*D
#define NH 4
#define DHM 64      // DI/NH
#define DHS 32      // D/NH
#define NROWS (BB*SS)   // 32768

#define WAVE_SYNC() do { asm volatile("s_waitcnt lgkmcnt(0)" ::: "memory"); __builtin_amdgcn_wave_barrier(); } while (0)

typedef __attribute__((ext_vector_type(8))) short short8;
typedef __attribute__((ext_vector_type(4))) float f32x4;
typedef __attribute__((ext_vector_type(2))) float f32x2;
typedef __attribute__((ext_vector_type(2))) int i32x2;

__device__ __forceinline__ float sigmoidf_(float x) { return 1.f / (1.f + __expf(-x)); }
__device__ __forceinline__ float siluf_(float x) { return x / (1.f + __expf(-x)); }
// stable log_sigmoid
__device__ __forceinline__ float logsigf_(float x) {
    return (x >= 0.f) ? -log1pf(__expf(-x)) : x - log1pf(__expf(x));
}
__device__ __forceinline__ float tanhf_(float x) {
    float e = __expf(2.f * x);
    return 1.f - 2.f / (e + 1.f);
}
// fp32 -> bf16 bits, round-to-nearest-even (inputs are finite)
__device__ __forceinline__ ushort bf16u(float x) {
    unsigned u = __float_as_uint(x);
    u += 0x7fffu + ((u >> 16) & 1u);
    return (ushort)(u >> 16);
}
__device__ __forceinline__ float rdlane(float v, int lane) {
    return __int_as_float(__builtin_amdgcn_readlane(__float_as_int(v), lane));
}
// DPP add: x + dpp(x) with given ctrl (VALU-speed cross-lane; bound_ctrl=1 -> 0 fill)
#define DPPADD(x, ctrl) ((x) + __int_as_float(__builtin_amdgcn_update_dpp(0, __float_as_int(x), (ctrl), 0xf, 0xf, true)))

// ---------------- fp32 -> bf16 copy ----------------
__global__ __launch_bounds__(256) void tobf16_kernel(const float* __restrict__ src,
        ushort* __restrict__ dst, int n) {
    int i = blockIdx.x * 256 + threadIdx.x;
    if (i < n) dst[i] = bf16u(src[i]);
}

// ---------------- densify sLSTM block-diag gate weights -> bf16 [i2][pair][256][128] ----------------
// Output channel layout per pair: oc = h*64 + l, l<32 -> gate0 ch l, l>=32 -> gate1 ch l-32.
// (pair 0: gates i,f from xc;  pair 1: gates z,o from xn)
__global__ __launch_bounds__(256) void densify_kernel(const float* __restrict__ wi,
        const float* __restrict__ wf, const float* __restrict__ wz,
        const float* __restrict__ wo, ushort* __restrict__ dst) {
    int idx = blockIdx.x * 256 + threadIdx.x;   // 2*2*256*128 = 262144
    int t = idx & 127;
    int oc = (idx >> 7) & 255;
    int pair = (idx >> 15) & 1;
    int i2 = idx >> 16;
    int h = oc >> 6, l = oc & 63, gate = (l >> 5) & 1, e = l & 31;
    const float* w = pair == 0 ? (gate == 0 ? wi : wf) : (gate == 0 ? wz : wo);
    float val = ((t >> 5) == h) ? w[i2 * 4096 + h * 1024 + e * 32 + (t & 31)] : 0.f;
    dst[idx] = bf16u(val);
}

// ---------------- embedding ----------------
__global__ __launch_bounds__(256) void embed_kernel(const int* __restrict__ x,
        const float* __restrict__ emb, float* __restrict__ h, int total) {
    int i = blockIdx.x * 256 + threadIdx.x;
    if (i >= total) return;
    int row = i >> 7;          // D=128
    int c = i & 127;
    h[i] = emb[x[row] * DD + c];
}

// ---------------- LayerNorm over D=128 (block=64 threads, 1 row); fp32 + bf16 out ----------------
__global__ __launch_bounds__(64) void ln128_kernel(const float* __restrict__ x,
        const float* __restrict__ w, float* __restrict__ out, ushort* __restrict__ outb) {
    int row = blockIdx.x;
    int lane = threadIdx.x;
    const float* xr = x + (size_t)row * DD;
    float a = xr[lane], b = xr[lane + 64];
    float s1 = a + b, s2 = a * a + b * b;
    #pragma unroll
    for (int o = 32; o; o >>= 1) { s1 += __shfl_xor(s1, o); s2 += __shfl_xor(s2, o); }
    float mu = s1 * (1.f / 128.f);
    float var = s2 * (1.f / 128.f) - mu * mu;
    float inv = rsqrtf(var + 1e-5f);
    float va = (a - mu) * inv * w[lane];
    float vb = (b - mu) * inv * w[lane + 64];
    float* orow = out + (size_t)row * DD;
    orow[lane] = va; orow[lane + 64] = vb;
    ushort* brow = outb + (size_t)row * DD;
    brow[lane] = bf16u(va); brow[lane + 64] = bf16u(vb);
}

// ---------------- bf16 MFMA GEMM: C[M,N] (+)= A[M,K](lda) @ W[N,K]^T ----------------
// 128x128 tile, BK=32, 4 waves (2x2 of 64x64), XOR-swizzled 16B chunks in LDS.
__global__ __launch_bounds__(256, 2) void gemm_bf16_kernel(const ushort* __restrict__ A, int lda,
        const ushort* __restrict__ W, float* __restrict__ C, int ldc, int K, int addC) {
    __shared__ ushort As[128 * 32];
    __shared__ ushort Bs[128 * 32];
    int m0 = blockIdx.x * 128;
    int n0 = blockIdx.y * 128;
    int tid = threadIdx.x;
    int wv = tid >> 6, l = tid & 63;
    int lr = l & 15, lg = l >> 4, g4 = lg * 4;
    int wr = wv >> 1, wc = wv & 1;
    int sr = tid >> 1;                  // staging row 0..127
    int sc = (tid & 1) * 2;             // staging chunk base {0,2}

    f32x4 acc[4][4] = {};
    for (int k0 = 0; k0 < K; k0 += 32) {
        __syncthreads();
        #pragma unroll
        for (int u = 0; u < 2; ++u) {
            int c = sc + u;
            uint4 av = *(const uint4*)(A + (size_t)(m0 + sr) * lda + k0 + c * 8);
            *(uint4*)(As + sr * 32 + ((c ^ (sr & 3)) * 8)) = av;
            uint4 wv4 = *(const uint4*)(W + (size_t)(n0 + sr) * K + k0 + c * 8);
            *(uint4*)(Bs + sr * 32 + ((c ^ (sr & 3)) * 8)) = wv4;
        }
        __syncthreads();
        short8 af[4], bf[4];
        #pragma unroll
        for (int fm = 0; fm < 4; ++fm) {
            int row = wr * 64 + fm * 16 + lr;
            af[fm] = *(const short8*)(As + row * 32 + ((lg ^ (row & 3)) * 8));
        }
        #pragma unroll
        for (int fn = 0; fn < 4; ++fn) {
            int row = wc * 64 + fn * 16 + lr;
            bf[fn] = *(const short8*)(Bs + row * 32 + ((lg ^ (row & 3)) * 8));
        }
        #pragma unroll
        for (int fm = 0; fm < 4; ++fm)
            #pragma unroll
            for (int fn = 0; fn < 4; ++fn)
                acc[fm][fn] = __builtin_amdgcn_mfma_f32_16x16x32_bf16(af[fm], bf[fn], acc[fm][fn], 0, 0, 0);
    }
    #pragma unroll
    for (int fm = 0; fm < 4; ++fm) {
        #pragma unroll
        for (int fn = 0; fn < 4; ++fn) {
            #pragma unroll
            for (int r = 0; r < 4; ++r) {
                size_t idx = (size_t)(m0 + wr * 64 + fm * 16 + g4 + r) * ldc + n0 + wc * 64 + fn * 16 + lr;
                if (addC) C[idx] += acc[fm][fn][r]; else C[idx] = acc[fm][fn][r];
            }
        }
    }
}

// ---------------- depthwise causal conv (K=4) + silu (fp32 out + optional bf16 out) ----------------
__global__ __launch_bounds__(256) void conv_silu_kernel(const float* __restrict__ x, int ldx, int C,
        const float* __restrict__ w, const float* __restrict__ bias,
        float* __restrict__ out, int ldo, ushort* __restrict__ outb, int total) {
    int i = blockIdx.x * 256 + threadIdx.x;
    if (i >= total) return;
    int c = i % C;
    size_t row = (size_t)(i / C);
    int s = (int)(row & (SS - 1));
    float acc = bias[c];
    #pragma unroll
    for (int j = 0; j < 4; ++j) {
        int ss = s - 3 + j;
        if (ss >= 0) acc += x[(row + (size_t)(ss - s)) * ldx + c] * w[c * 4 + j];
    }
    float val = siluf_(acc);
    out[row * ldo + c] = val;
    if (outb) outb[row * ldo + c] = bf16u(val);
}

// ---------------- mLSTM block-diagonal q,k,v (8x8 blocks) + bf16 per-head copies ----------------
__global__ __launch_bounds__(256) void mqkv_kernel(const float* __restrict__ xca,
        const float* __restrict__ xz, const float* __restrict__ qw,
        const float* __restrict__ kw, const float* __restrict__ vw,
        float* __restrict__ q, float* __restrict__ k, float* __restrict__ v,
        ushort* __restrict__ qb16, ushort* __restrict__ kb16, int total) {
    int i = blockIdx.x * 256 + threadIdx.x;
    if (i >= total) return;
    int c = i & 255;
    size_t row = (size_t)(i >> 8);
    int nb = c >> 3, e = c & 7;
    const float* xc8 = xca + row * 256 + nb * 8;
    const float* xi8 = xz + row * 512 + nb * 8;
    const float* qw8 = qw + (size_t)(nb * 8 + e) * 8;
    const float* kw8 = kw + (size_t)(nb * 8 + e) * 8;
    const float* vw8 = vw + (size_t)(nb * 8 + e) * 8;
    float aq = 0.f, ak = 0.f, av = 0.f;
    #pragma unroll
    for (int t = 0; t < 8; ++t) {
        float xcv = xc8[t], xiv = xi8[t];
        aq += xcv * qw8[t];
        ak += xcv * kw8[t];
        av += xiv * vw8[t];
    }
    q[i] = aq; k[i] = ak; v[i] = av;
    // bf16 per-head layout [bh][s][64] for the MFMA core
    int h2 = c >> 6, dd = c & 63;
    size_t be = ((((row >> 8) << 2) + h2) * 256 + (row & 255)) * 64 + dd;
    qb16[be] = bf16u(aq);
    kb16[be] = bf16u(ak);
}

// ---------------- mLSTM input/forget gate projections (dot-768 per (row,h)) ----------------
__global__ __launch_bounds__(256) void mgate_kernel(const float* __restrict__ q,
        const float* __restrict__ k, const float* __restrict__ v,
        const float* __restrict__ igw, const float* __restrict__ igb,
        const float* __restrict__ fgw, const float* __restrict__ fgb,
        float* __restrict__ ip, float* __restrict__ fp) {
    int row = blockIdx.x;
    int t = threadIdx.x;
    float qv = q[(size_t)row * 256 + t];
    float kv = k[(size_t)row * 256 + t];
    float vv = v[(size_t)row * 256 + t];
    float pi[4], pf[4];
    #pragma unroll
    for (int hh = 0; hh < 4; ++hh) {
        const float* wi = igw + hh * 768;
        const float* wf = fgw + hh * 768;
        pi[hh] = qv * wi[t] + kv * wi[256 + t] + vv * wi[512 + t];
        pf[hh] = qv * wf[t] + kv * wf[256 + t] + vv * wf[512 + t];
    }
    #pragma unroll
    for (int hh = 0; hh < 4; ++hh) {
        #pragma unroll
        for (int o = 32; o; o >>= 1) {
            pi[hh] += __shfl_xor(pi[hh], o);
            pf[hh] += __shfl_xor(pf[hh], o);
        }
    }
    __shared__ float red[2][4][4];
    int wave = t >> 6, lane = t & 63;
    if (lane == 0) {
        #pragma unroll
        for (int hh = 0; hh < 4; ++hh) { red[0][wave][hh] = pi[hh]; red[1][wave][hh] = pf[hh]; }
    }
    __syncthreads();
    if (t < 8) {
        int g = t >> 2, hh = t & 3;
        float s = red[g][0][hh] + red[g][1][hh] + red[g][2][hh] + red[g][3][hh];
        int b = row >> 8, sidx = row & 255;
        size_t oidx = (size_t)(b * NH + hh) * SS + sidx;
        if (g == 0) ip[oidx] = s + igb[hh];
        else        fp[oidx] = s + fgb[hh];
    }
}

// ---------------- mLSTM decay prefix scan: L (cum log-sigmoid), E = ip - L, PM = prefix-max(E) ----------------
__global__ __launch_bounds__(64) void mprep_kernel(const float* __restrict__ ip,
        const float* __restrict__ fp, float* __restrict__ L,
        float* __restrict__ E, float* __restrict__ PM) {
    int bh = blockIdx.x;
    int lane = threadIdx.x;
    __shared__ float sfp[SS], sip[SS], sL[SS], sE[SS], sPM[SS];
    for (int u = lane; u < SS; u += 64) {
        sfp[u] = fp[(size_t)bh * SS + u];
        sip[u] = ip[(size_t)bh * SS + u];
    }
    __syncthreads();
    if (lane == 0) {
        float run = 0.f, pm = -INFINITY;
        for (int j = 0; j < SS; ++j) {
            run += logsigf_(sfp[j]);
            float e = sip[j] - run;
            pm = fmaxf(pm, e);
            sL[j] = run; sE[j] = e; sPM[j] = pm;
        }
    }
    __syncthreads();
    for (int u = lane; u < SS; u += 64) {
        L[(size_t)bh * SS + u] = sL[u];
        E[(size_t)bh * SS + u] = sE[u];
        PM[(size_t)bh * SS + u] = sPM[u];
    }
}

// ---------------- V transpose to [bh][64][256] bf16 ----------------
__global__ __launch_bounds__(256) void vtrans_kernel(const float* __restrict__ v,
        ushort* __restrict__ vt) {
    int blk = blockIdx.x;
    int st = blk & 3, bh = blk >> 2;
    int b = bh >> 2, h = bh & 3;
    int tid = threadIdx.x;
    __shared__ float tile[64][65];
    int s0 = st * 64;
    #pragma unroll
    for (int u = 0; u < 16; ++u) {
        int idx = u * 256 + tid;
        int sl = idx >> 6, dl = idx & 63;
        tile[sl][dl] = v[((size_t)(b * 256 + s0 + sl)) * 256 + h * 64 + dl];
    }
    __syncthreads();
    #pragma unroll
    for (int u = 0; u < 16; ++u) {
        int idx = u * 256 + tid;
        int dl = idx >> 6, sl = idx & 63;
        vt[((size_t)bh * 64 + dl) * 256 + s0 + sl] = bf16u(tile[sl][dl]);
    }
}

// ---------------- mLSTM parallel core via MFMA ----------------
__global__ __launch_bounds__(256, 2) void mlstm_mfma_kernel(
        const ushort* __restrict__ qb, const ushort* __restrict__ kb,
        const ushort* __restrict__ vt, const float* __restrict__ Lg,
        const float* __restrict__ Eg, const float* __restrict__ PMg,
        float* __restrict__ hmout) {
    int bh = blockIdx.x;
    int b = bh >> 2, h = bh & 3;
    int tid = threadIdx.x;
    int wv = tid >> 6, l = tid & 63;
    int lr = l & 15, lg = l >> 4, g4 = lg * 4;

    __shared__ ushort Kb[16384];     // 32 KB
    __shared__ ushort Vt[16384];     // 32 KB
    __shared__ ushort Pl[4 * 640];   // per-wave 16x40 bf16
    __shared__ float sE[SS], sPM[SS], sL[SS];

    const size_t gb16 = (size_t)bh * 16384;
    #pragma unroll
    for (int p2 = 0; p2 < 8; ++p2) {
        int id = p2 * 256 + tid;
        int r = id >> 3, c = id & 7;
        uint4 kval = *(const uint4*)(kb + gb16 + r * 64 + c * 8);
        *(uint4*)(Kb + r * 64 + ((c ^ (r & 7)) * 8)) = kval;
        int d = id >> 5, c2 = id & 31;
        uint4 vval = *(const uint4*)(vt + gb16 + d * 256 + c2 * 8);
        *(uint4*)(Vt + d * 256 + ((c2 ^ (d & 7)) * 8)) = vval;
    }
    sE[tid]  = Eg[(size_t)bh * SS + tid];
    sPM[tid] = PMg[(size_t)bh * SS + tid];
    sL[tid]  = Lg[(size_t)bh * SS + tid];
    __syncthreads();

    f32x4 O[4][4] = {};
    float csum[4][4] = {};
    const int pmap[4] = {wv, 7 - wv, 8 + wv, 15 - wv};
    ushort* Pw = Pl + wv * 640;
    size_t obase = (size_t)b * SS * 512 + h * 64;

    #pragma unroll
    for (int rf = 0; rf < 4; ++rf) {
        int p = pmap[rf];
        int r0 = p * 16;
        short8 qf0 = *(const short8*)(qb + gb16 + (r0 + lr) * 64 + lg * 8);
        short8 qf1 = *(const short8*)(qb + gb16 + (r0 + lr) * 64 + 32 + lg * 8);
        float pmv[4], lv[4];
        #pragma unroll
        for (int r = 0; r < 4; ++r) { pmv[r] = sPM[r0 + g4 + r]; lv[r] = sL[r0 + g4 + r]; }
        int jtmax = r0 >> 5;
        #pragma unroll 1
        for (int jt = 0; jt <= jtmax; ++jt) {
            int jb = jt * 32;
            f32x4 s0 = {0.f, 0.f, 0.f, 0.f}, s1 = {0.f, 0.f, 0.f, 0.f};
            {
                int j = jb + lr;
                int sw = j & 7;
                short8 k00 = *(const short8*)(Kb + j * 64 + ((lg)     ^ sw) * 8);
                short8 k01 = *(const short8*)(Kb + j * 64 + ((4 + lg) ^ sw) * 8);
                int j2 = jb + 16 + lr;
                int sw2 = j2 & 7;
                short8 k10 = *(const short8*)(Kb + j2 * 64 + ((lg)     ^ sw2) * 8);
                short8 k11 = *(const short8*)(Kb + j2 * 64 + ((4 + lg) ^ sw2) * 8);
                s0 = __builtin_amdgcn_mfma_f32_16x16x32_bf16(qf0, k00, s0, 0, 0, 0);
                s0 = __builtin_amdgcn_mfma_f32_16x16x32_bf16(qf1, k01, s0, 0, 0, 0);
                s1 = __builtin_amdgcn_mfma_f32_16x16x32_bf16(qf0, k10, s1, 0, 0, 0);
                s1 = __builtin_amdgcn_mfma_f32_16x16x32_bf16(qf1, k11, s1, 0, 0, 0);
            }
            float e0 = sE[jb + lr], e1 = sE[jb + 16 + lr];
            int j0 = jb + lr, j1 = jb + 16 + lr;
            #pragma unroll
            for (int r = 0; r < 4; ++r) {
                int i = r0 + g4 + r;
                float sc0 = (j0 <= i) ? s0[r] * 0.125f * __expf(e0 - pmv[r]) : 0.f;
                float sc1 = (j1 <= i) ? s1[r] * 0.125f * __expf(e1 - pmv[r]) : 0.f;
                csum[rf][r] += sc0 + sc1;
                Pw[(g4 + r) * 40 + lr] = bf16u(sc0);
                Pw[(g4 + r) * 40 + 16 + lr] = bf16u(sc1);
            }
            WAVE_SYNC();
            short8 pf = *(const short8*)(Pw + lr * 40 + lg * 8);
            #pragma unroll
            for (int dc = 0; dc < 4; ++dc) {
                int d = dc * 16 + lr;
                int chunk = (jt * 4 + lg) ^ (d & 7);
                short8 vf = *(const short8*)(Vt + d * 256 + chunk * 8);
                O[rf][dc] = __builtin_amdgcn_mfma_f32_16x16x32_bf16(pf, vf, O[rf][dc], 0, 0, 0);
            }
        }
        float rinv[4];
        #pragma unroll
        for (int r = 0; r < 4; ++r) {
            float cs = csum[rf][r];
            cs += __shfl_xor(cs, 1); cs += __shfl_xor(cs, 2);
            cs += __shfl_xor(cs, 4); cs += __shfl_xor(cs, 8);
            float nrm = fmaxf(fabsf(cs), __expf(-(lv[r] + pmv[r]))) + 1e-6f;
            rinv[r] = 1.f / nrm;
        }
        #pragma unroll
        for (int dc = 0; dc < 4; ++dc)
            #pragma unroll
            for (int r = 0; r < 4; ++r)
                hmout[obase + (size_t)(r0 + g4 + r) * 512 + dc * 16 + lr] = O[rf][dc][r] * rinv[r];
    }
}

// ---------------- mLSTM post: group-LN(64) + skip + silu(z) -> bf16 [NR][256] ----------------
__global__ __launch_bounds__(256) void mpost_kernel(const float* __restrict__ xzbuf,
        const float* __restrict__ xca, const float* __restrict__ onw,
        const float* __restrict__ skip, ushort* __restrict__ outb) {
    int row = blockIdx.x;
    int t = threadIdx.x;
    size_t base = (size_t)row * 512;
    float hm = xzbuf[base + t];
    float s1 = hm, s2 = hm * hm;
    #pragma unroll
    for (int o = 32; o; o >>= 1) { s1 += __shfl_xor(s1, o); s2 += __shfl_xor(s2, o); }
    float mu = s1 * (1.f / 64.f);
    float var = s2 * (1.f / 64.f) - mu * mu;
    float xnv = (hm - mu) * rsqrtf(var + 1e-5f) * onw[t];
    float z = xzbuf[base + 256 + t];
    float val = (xnv + skip[t] * xca[(size_t)row * 256 + t]) * siluf_(z);
    outb[(size_t)row * 256 + t] = bf16u(val);
}

// ---------------- sLSTM sequential scan: TWO chains per wave (same head, b and b+64) ----------------
// gif[row][256]: col h*64+l = x-gate (l<32: i ch l, l>=32: f ch l-32); gzo likewise (z,o).
// Shared w01 (same head), independent state -> compiler interleaves the two chains' code,
// filling latency stalls of the single in-order wave (R6's bottleneck: 0.5 waves/SIMD).
__global__ __launch_bounds__(64) void slstm_scan_kernel(const float* __restrict__ gif,
        const float* __restrict__ gzo, const float* __restrict__ rec_w,
        const float* __restrict__ bias, const float* __restrict__ gnw,
        float* __restrict__ hbuf) {
    int bi = blockIdx.x;               // 256 blocks
    int h = bi & 3;
    int bA = bi >> 2;                  // 0..63
    int bB = bA + 64;
    int l = threadIdx.x;
    int c = l & 31;
    bool lo = (l < 32);
    f32x2 w01[32];   // .x -> col l (raw0), .y -> col 64+l (raw1); shared by both chains
    const float* wp = rec_w + (size_t)h * 4096 + l;
    #pragma unroll
    for (int d = 0; d < 32; ++d) {
        w01[d].x = wp[d * 128];
        w01[d].y = wp[d * 128 + 64];
    }
    float b0 = bias[h * 128 + l];
    float b1 = bias[h * 128 + 64 + l];
    float gw = gnw[h * 32 + c];
    float cstA = 0.f, nstA = 0.f, mstA = 0.f, hAr = 0.f;
    float cstB = 0.f, nstB = 0.f, mstB = 0.f, hBr = 0.f;
    size_t gbA = (size_t)bA * SS * 256 + h * 64 + l;
    size_t gbB = (size_t)bB * SS * 256 + h * 64 + l;
    size_t hbA = (size_t)bA * SS * 128 + h * 32 + c;
    size_t hbB = (size_t)bB * SS * 128 + h * 32 + c;
    float pg0A[4], pg1A[4], phA[4], pg0B[4], pg1B[4], phB[4];
    #pragma unroll
    for (int u = 0; u < 4; ++u) {
        pg0A[u] = gif[gbA + (size_t)u * 256];
        pg1A[u] = gzo[gbA + (size_t)u * 256];
        phA[u]  = hbuf[hbA + (size_t)u * 128];
        pg0B[u] = gif[gbB + (size_t)u * 256];
        pg1B[u] = gzo[gbB + (size_t)u * 256];
        phB[u]  = hbuf[hbB + (size_t)u * 128];
    }
    for (int s = 0; s < SS; s += 4) {
        #pragma unroll
        for (int u = 0; u < 4; ++u) {
            // recurrent matvecs for both chains (independent -> interleaved by scheduler)
            f32x2 aA0 = {0.f, 0.f}, aA1 = {0.f, 0.f}, aA2 = {0.f, 0.f}, aA3 = {0.f, 0.f};
            f32x2 aB0 = {0.f, 0.f}, aB1 = {0.f, 0.f}, aB2 = {0.f, 0.f}, aB3 = {0.f, 0.f};
            #pragma unroll
            for (int d = 0; d < 32; d += 4) {
                float hA0 = rdlane(hAr, d), hA1 = rdlane(hAr, d + 1);
                float hA2 = rdlane(hAr, d + 2), hA3 = rdlane(hAr, d + 3);
                float hB0 = rdlane(hBr, d), hB1 = rdlane(hBr, d + 1);
                float hB2 = rdlane(hBr, d + 2), hB3 = rdlane(hBr, d + 3);
                aA0 += w01[d] * hA0;     aB0 += w01[d] * hB0;
                aA1 += w01[d + 1] * hA1; aB1 += w01[d + 1] * hB1;
                aA2 += w01[d + 2] * hA2; aB2 += w01[d + 2] * hB2;
                aA3 += w01[d + 3] * hA3; aB3 += w01[d + 3] * hB3;
            }
            f32x2 sA = (aA0 + aA1) + (aA2 + aA3);
            f32x2 sB = (aB0 + aB1) + (aB2 + aB3);
            float raw0A = pg0A[u] + sA.x + b0;
            float raw1A = pg1A[u] + sA.y + b1;
            float raw0B = pg0B[u] + sB.x + b0;
            float raw1B = pg1B[u] + sB.y + b1;
            float hcurA = phA[u], hcurB = phB[u];
            int s4 = s + 4 + u;
            if (s4 < SS) {
                pg0A[u] = gif[gbA + (size_t)s4 * 256];
                pg1A[u] = gzo[gbA + (size_t)s4 * 256];
                phA[u]  = hbuf[hbA + (size_t)s4 * 128];
                pg0B[u] = gif[gbB + (size_t)s4 * 256];
                pg1B[u] = gzo[gbB + (size_t)s4 * 256];
                phB[u]  = hbuf[hbB + (size_t)s4 * 128];
            }
            // half-swap via permlane32_swap (VALU)
            i32x2 r0pA = __builtin_amdgcn_permlane32_swap(__float_as_int(raw0A), __float_as_int(raw0A), false, false);
            i32x2 r1pA = __builtin_amdgcn_permlane32_swap(__float_as_int(raw1A), __float_as_int(raw1A), false, false);
            i32x2 r0pB = __builtin_amdgcn_permlane32_swap(__float_as_int(raw0B), __float_as_int(raw0B), false, false);
            i32x2 r1pB = __builtin_amdgcn_permlane32_swap(__float_as_int(raw1B), __float_as_int(raw1B), false, false);
            float q0A = __int_as_float(lo ? r0pA.y : r0pA.x);
            float q1A = __int_as_float(lo ? r1pA.y : r1pA.x);
            float q0B = __int_as_float(lo ? r0pB.y : r0pB.x);
            float q1B = __int_as_float(lo ? r1pB.y : r1pB.x);
            float irawA = lo ? raw0A : q0A, zrawA = lo ? raw1A : q1A;
            float frawA = lo ? q0A : raw0A, orawA = lo ? q1A : raw1A;
            float irawB = lo ? raw0B : q0B, zrawB = lo ? raw1B : q1B;
            float frawB = lo ? q0B : raw0B, orawB = lo ? q1B : raw1B;
            // chain A gates
            float lfmA = mstA + fminf(frawA, 0.f) - __logf(1.f + __expf(-fabsf(frawA)));
            float mnewA = fmaxf(irawA, lfmA);
            float igA = __expf(irawA - mnewA);
            float fgA = __expf(lfmA - mnewA);
            float tzA = 1.f - 2.f * __builtin_amdgcn_rcpf(__expf(2.f * zrawA) + 1.f);
            cstA = fgA * cstA + igA * tzA;
            nstA = fgA * nstA + igA;
            mstA = mnewA;
            float sgA = __builtin_amdgcn_rcpf(1.f + __expf(-orawA));
            float hvA = sgA * cstA * __builtin_amdgcn_rcpf(nstA);
            hAr = hvA;
            // chain B gates
            float lfmB = mstB + fminf(frawB, 0.f) - __logf(1.f + __expf(-fabsf(frawB)));
            float mnewB = fmaxf(irawB, lfmB);
            float igB = __expf(irawB - mnewB);
            float fgB = __expf(lfmB - mnewB);
            float tzB = 1.f - 2.f * __builtin_amdgcn_rcpf(__expf(2.f * zrawB) + 1.f);
            cstB = fgB * cstB + igB * tzB;
            nstB = fgB * nstB + igB;
            mstB = mnewB;
            float sgB = __builtin_amdgcn_rcpf(1.f + __expf(-orawB));
            float hvB = sgB * cstB * __builtin_amdgcn_rcpf(nstB);
            hBr = hvB;
            // fused group-LN(32) + residual (64-lane DPP sum = 2x 32-sum); off inter-step path
            float s1A = hvA, s2A = hvA * hvA, s1B = hvB, s2B = hvB * hvB;
            s1A = DPPADD(s1A, 0x111); s2A = DPPADD(s2A, 0x111); s1B = DPPADD(s1B, 0x111); s2B = DPPADD(s2B, 0x111);
            s1A = DPPADD(s1A, 0x112); s2A = DPPADD(s2A, 0x112); s1B = DPPADD(s1B, 0x112); s2B = DPPADD(s2B, 0x112);
            s1A = DPPADD(s1A, 0x114); s2A = DPPADD(s2A, 0x114); s1B = DPPADD(s1B, 0x114); s2B = DPPADD(s2B, 0x114);
            s1A = DPPADD(s1A, 0x118); s2A = DPPADD(s2A, 0x118); s1B = DPPADD(s1B, 0x118); s2B = DPPADD(s2B, 0x118);
            s1A = DPPADD(s1A, 0x142); s2A = DPPADD(s2A, 0x142); s1B = DPPADD(s1B, 0x142); s2B = DPPADD(s2B, 0x142);
            s1A = DPPADD(s1A, 0x143); s2A = DPPADD(s2A, 0x143); s1B = DPPADD(s1B, 0x143); s2B = DPPADD(s2B, 0x143);
            float muA = rdlane(s1A, 63) * (1.f / 64.f);
            float varA = rdlane(s2A, 63) * (1.f / 64.f) - muA * muA;
            float muB = rdlane(s1B, 63) * (1.f / 64.f);
            float varB = rdlane(s2B, 63) * (1.f / 64.f) - muB * muB;
            float outvA = (hvA - muA) * rsqrtf(varA + 1e-5f) * gw;
            float outvB = (hvB - muB) * rsqrtf(varB + 1e-5f) * gw;
            if (lo) {
                hbuf[hbA + (size_t)(s + u) * 128] = hcurA + outvA;
                hbuf[hbB + (size_t)(s + u) * 128] = hcurB + outvB;
            }
        }
    }
}

// ---------------- gated-GELU (exact erf) -> bf16 ----------------
__global__ __launch_bounds__(256) void geluglu_kernel(const float* __restrict__ xzbuf,
        ushort* __restrict__ gg, int total) {
    int i = blockIdx.x * 256 + threadIdx.x;
    if (i >= total) return;
    int c = i & 255;
    size_t row = (size_t)(i >> 8);
    float g = xzbuf[row * 512 + c];
    float u = xzbuf[row * 512 + 256 + c];
    float ge = 0.5f * g * (1.f + erff(g * 0.70710678118654752f));
    gg[i] = bf16u(ge * u);
}

extern "C" void kernel_launch(void* const* d_in, const int* in_sizes, int n_in,
                              void* d_out, int out_size, void* d_ws, size_t ws_size,
                              hipStream_t stream) {
    const int*   x        = (const int*)d_in[0];
    const float* emb      = (const float*)d_in[1];
    const float* m_ln_w   = (const float*)d_in[2];
    const float* m_up_w   = (const float*)d_in[3];
    const float* m_conv_w = (const float*)d_in[4];
    const float* m_conv_b = (const float*)d_in[5];
    const float* m_q_w    = (const float*)d_in[6];
    const float* m_k_w    = (const float*)d_in[7];
    const float* m_v_w    = (const float*)d_in[8];
    const float* m_ig_w   = (const float*)d_in[9];
    const float* m_ig_b   = (const float*)d_in[10];
    const float* m_fg_w   = (const float*)d_in[11];
    const float* m_fg_b   = (const float*)d_in[12];
    const float* m_on_w   = (const float*)d_in[13];
    const float* m_skip   = (const float*)d_in[14];
    const float* m_down_w = (const float*)d_in[15];
    const float* s_ln1_w  = (const float*)d_in[16];
    const float* s_conv_w = (const float*)d_in[17];
    const float* s_conv_b = (const float*)d_in[18];
    const float* s_ig_w   = (const float*)d_in[19];
    const float* s_fg_w   = (const float*)d_in[20];
    const float* s_zg_w   = (const float*)d_in[21];
    const float* s_og_w   = (const float*)d_in[22];
    const float* s_rec_w  = (const float*)d_in[23];
    const float* s_bias   = (const float*)d_in[24];
    const float* s_gn_w   = (const float*)d_in[25];
    const float* s_ln2_w  = (const float*)d_in[26];
    const float* s_ff_up_w   = (const float*)d_in[27];
    const float* s_ff_down_w = (const float*)d_in[28];
    const float* post_norm_w = (const float*)d_in[29];
    float* out = (float*)d_out;

    float* ws = (float*)d_ws;
    const size_t NR = NROWS;
    float* h   = ws;                   // NR*128
    float* xn  = h   + NR * 128;       // NR*128 fp32 (later qb16 alias)
    float* xz  = xn  + NR * 128;       // NR*512
    float* xca = xz  + NR * 512;       // NR*256
    float* q   = xca + NR * 256;       // NR*256 (q fp32; later mpostb bf16; later gif fp32)
    float* k   = q   + NR * 256;       // NR*256 (k fp32; later vtb bf16; later gzo fp32)
    float* v   = k   + NR * 256;       // NR*256 (v fp32)
    float* gip = v   + NR * 256;       // 512*256
    float* gfp = gip + 512 * 256;
    float* gL  = gfp + 512 * 256;
    float* gE  = gL  + 512 * 256;
    float* gPM = gE  + 512 * 256;
    float* extra = gPM + 512 * 256;
    // bf16 regions
    ushort* xnb   = (ushort*)extra;                    // NR*128 bf16
    ushort* upb   = (ushort*)(extra + NR * 64);        // 512*128
    ushort* downb = upb + 512 * 128;                   // 128*256
    ushort* ffupb = downb + 128 * 256;                 // 2*512*128
    ushort* ffdownb = ffupb + 2 * 512 * 128;           // 2*128*256
    ushort* sgwb  = ffdownb + 2 * 128 * 256;           // 2*2*256*128
    // aliases (regions dead at time of use)
    ushort* qb16   = (ushort*)xn;     // NR*256 bf16
    ushort* kb16   = (ushort*)out;    // NR*256 bf16
    ushort* vtb    = (ushort*)k;      // NR*256 bf16
    ushort* mpostb = (ushort*)q;      // NR*256 bf16
    ushort* xcb    = (ushort*)(xca + NR * 128);   // NR*128 bf16
    ushort* ggb    = (ushort*)xca;    // NR*256 bf16
    float* gif = q;                   // NR*256 fp32
    float* gzo = k;                   // NR*256 fp32

    // ---- weight conversions ----
    tobf16_kernel<<<(512 * 128 + 255) / 256, 256, 0, stream>>>(m_up_w, upb, 512 * 128);
    tobf16_kernel<<<(128 * 256 + 255) / 256, 256, 0, stream>>>(m_down_w, downb, 128 * 256);
    tobf16_kernel<<<(2 * 512 * 128 + 255) / 256, 256, 0, stream>>>(s_ff_up_w, ffupb, 2 * 512 * 128);
    tobf16_kernel<<<(2 * 128 * 256 + 255) / 256, 256, 0, stream>>>(s_ff_down_w, ffdownb, 2 * 128 * 256);
    densify_kernel<<<(2 * 2 * 256 * 128) / 256, 256, 0, stream>>>(s_ig_w, s_fg_w, s_zg_w, s_og_w, sgwb);

    // ---- embedding + pre-LN ----
    embed_kernel<<<(NR * 128) / 256, 256, 0, stream>>>(x, emb, h, NR * 128);
    ln128_kernel<<<NR, 64, 0, stream>>>(h, m_ln_w, xn, xnb);
    // ---- mLSTM up-projection (bf16 MFMA) ----
    gemm_bf16_kernel<<<dim3(NR / 128, 4), 256, 0, stream>>>(xnb, 128, upb, xz, 512, 128, 0);
    // ---- causal conv + silu ----
    conv_silu_kernel<<<(NR * 256) / 256, 256, 0, stream>>>(xz, 512, 256, m_conv_w, m_conv_b, xca, 256, nullptr, NR * 256);
    // ---- block-diag q,k,v (+ bf16 copies) ----
    mqkv_kernel<<<(NR * 256) / 256, 256, 0, stream>>>(xca, xz, m_q_w, m_k_w, m_v_w, q, k, v, qb16, kb16, NR * 256);
    // ---- i/f gate projections ----
    mgate_kernel<<<NR, 256, 0, stream>>>(q, k, v, m_ig_w, m_ig_b, m_fg_w, m_fg_b, gip, gfp);
    // ---- decay prefix scan ----
    mprep_kernel<<<BB * NH, 64, 0, stream>>>(gip, gfp, gL, gE, gPM);
    // ---- V transpose to bf16 (into dead k fp32 space) ----
    vtrans_kernel<<<BB * NH * 4, 256, 0, stream>>>(v, vtb);
    // ---- mLSTM parallel core via MFMA (hm -> x_in half of xz) ----
    mlstm_mfma_kernel<<<BB * NH, 256, 0, stream>>>(qb16, kb16, vtb, gL, gE, gPM, xz);
    // ---- post: group-LN + skip + silu(z) -> bf16 (q region now dead) ----
    mpost_kernel<<<NR, 256, 0, stream>>>(xz, xca, m_on_w, m_skip, mpostb);
    // ---- down-projection + residual (bf16 MFMA, accumulate) ----
    gemm_bf16_kernel<<<dim3(NR / 128, 1), 256, 0, stream>>>(mpostb, 256, downb, h, 128, 256, 1);

    // ---- two sLSTM blocks ----
    for (int i2 = 0; i2 < 2; ++i2) {
        ln128_kernel<<<NR, 64, 0, stream>>>(h, s_ln1_w + i2 * 128, xn, xnb);
        conv_silu_kernel<<<(NR * 128) / 256, 256, 0, stream>>>(xn, 128, 128, s_conv_w + i2 * 128 * 4, s_conv_b + i2 * 128, xca, 128, xcb, NR * 128);
        // gates via dense bf16 GEMMs: [i|f]-perm = xc @ Wif'^T, [z|o]-perm = xn @ Wzo'^T
        gemm_bf16_kernel<<<dim3(NR / 128, 2), 256, 0, stream>>>(xcb, 128, sgwb + (size_t)(i2 * 2 + 0) * 256 * 128, gif, 256, 128, 0);
        gemm_bf16_kernel<<<dim3(NR / 128, 2), 256, 0, stream>>>(xnb, 128, sgwb + (size_t)(i2 * 2 + 1) * 256 * 128, gzo, 256, 128, 0);
        // scan with fused group-LN + residual into h (2 chains per wave)
        slstm_scan_kernel<<<BB * NH / 2, 64, 0, stream>>>(gif, gzo,
                s_rec_w + i2 * 4 * 32 * 128, s_bias + i2 * 4 * 128, s_gn_w + i2 * 128, h);
        ln128_kernel<<<NR, 64, 0, stream>>>(h, s_ln2_w + i2 * 128, xn, xnb);
        gemm_bf16_kernel<<<dim3(NR / 128, 4), 256, 0, stream>>>(xnb, 128, ffupb + (size_t)i2 * 512 * 128, xz, 512, 128, 0);
        geluglu_kernel<<<(NR * 256) / 256, 256, 0, stream>>>(xz, ggb, NR * 256);
        gemm_bf16_kernel<<<dim3(NR / 128, 1), 256, 0, stream>>>(ggb, 256, ffdownb + (size_t)i2 * 128 * 256, h, 128, 256, 1);
    }
    // ---- final LN -> out ----
    ln128_kernel<<<NR, 64, 0, stream>>>(h, post_norm_w, out, xnb);
}

// Round 8
// 1031.203 us; speedup vs baseline: 1.2404x; 1.2404x over previous
//
#include <hip/hip_runtime.h>
#include <hip/hip_bf16.h>

// Model dims (compile-time)
#define BB 128
#define SS 256
#define DD 128
#define DI 256      // 2*D
#define NH 4
#define DHM 64      // DI/NH
#define DHS 32      // D/NH
#define NROWS (BB*SS)   // 32768

#define WAVE_SYNC() do { asm volatile("s_waitcnt lgkmcnt(0)" ::: "memory"); __builtin_amdgcn_wave_barrier(); } while (0)

typedef __attribute__((ext_vector_type(8))) short short8;
typedef __attribute__((ext_vector_type(4))) float f32x4;
typedef __attribute__((ext_vector_type(2))) float f32x2;
typedef __attribute__((ext_vector_type(2))) int i32x2;

__device__ __forceinline__ float sigmoidf_(float x) { return 1.f / (1.f + __expf(-x)); }
__device__ __forceinline__ float siluf_(float x) { return x / (1.f + __expf(-x)); }
// stable log_sigmoid
__device__ __forceinline__ float logsigf_(float x) {
    return (x >= 0.f) ? -log1pf(__expf(-x)) : x - log1pf(__expf(x));
}
__device__ __forceinline__ float tanhf_(float x) {
    float e = __expf(2.f * x);
    return 1.f - 2.f / (e + 1.f);
}
// fp32 -> bf16 bits, round-to-nearest-even (inputs are finite)
__device__ __forceinline__ ushort bf16u(float x) {
    unsigned u = __float_as_uint(x);
    u += 0x7fffu + ((u >> 16) & 1u);
    return (ushort)(u >> 16);
}
__device__ __forceinline__ float rdlane(float v, int lane) {
    return __int_as_float(__builtin_amdgcn_readlane(__float_as_int(v), lane));
}
// DPP add: x + dpp(x) with given ctrl (VALU-speed cross-lane; bound_ctrl=1 -> 0 fill)
#define DPPADD(x, ctrl) ((x) + __int_as_float(__builtin_amdgcn_update_dpp(0, __float_as_int(x), (ctrl), 0xf, 0xf, true)))

// ---------------- fp32 -> bf16 copy ----------------
__global__ __launch_bounds__(256) void tobf16_kernel(const float* __restrict__ src,
        ushort* __restrict__ dst, int n) {
    int i = blockIdx.x * 256 + threadIdx.x;
    if (i < n) dst[i] = bf16u(src[i]);
}

// ---------------- densify sLSTM block-diag gate weights -> bf16 [i2][pair][256][128] ----------------
// Output channel layout per pair: oc = h*64 + l, l<32 -> gate0 ch l, l>=32 -> gate1 ch l-32.
// (pair 0: gates i,f from xc;  pair 1: gates z,o from xn)
__global__ __launch_bounds__(256) void densify_kernel(const float* __restrict__ wi,
        const float* __restrict__ wf, const float* __restrict__ wz,
        const float* __restrict__ wo, ushort* __restrict__ dst) {
    int idx = blockIdx.x * 256 + threadIdx.x;   // 2*2*256*128 = 262144
    int t = idx & 127;
    int oc = (idx >> 7) & 255;
    int pair = (idx >> 15) & 1;
    int i2 = idx >> 16;
    int h = oc >> 6, l = oc & 63, gate = (l >> 5) & 1, e = l & 31;
    const float* w = pair == 0 ? (gate == 0 ? wi : wf) : (gate == 0 ? wz : wo);
    float val = ((t >> 5) == h) ? w[i2 * 4096 + h * 1024 + e * 32 + (t & 31)] : 0.f;
    dst[idx] = bf16u(val);
}

// ---------------- embedding ----------------
__global__ __launch_bounds__(256) void embed_kernel(const int* __restrict__ x,
        const float* __restrict__ emb, float* __restrict__ h, int total) {
    int i = blockIdx.x * 256 + threadIdx.x;
    if (i >= total) return;
    int row = i >> 7;          // D=128
    int c = i & 127;
    h[i] = emb[x[row] * DD + c];
}

// ---------------- LayerNorm over D=128 (block=64 threads, 1 row); fp32 + bf16 out ----------------
__global__ __launch_bounds__(64) void ln128_kernel(const float* __restrict__ x,
        const float* __restrict__ w, float* __restrict__ out, ushort* __restrict__ outb) {
    int row = blockIdx.x;
    int lane = threadIdx.x;
    const float* xr = x + (size_t)row * DD;
    float a = xr[lane], b = xr[lane + 64];
    float s1 = a + b, s2 = a * a + b * b;
    #pragma unroll
    for (int o = 32; o; o >>= 1) { s1 += __shfl_xor(s1, o); s2 += __shfl_xor(s2, o); }
    float mu = s1 * (1.f / 128.f);
    float var = s2 * (1.f / 128.f) - mu * mu;
    float inv = rsqrtf(var + 1e-5f);
    float va = (a - mu) * inv * w[lane];
    float vb = (b - mu) * inv * w[lane + 64];
    float* orow = out + (size_t)row * DD;
    orow[lane] = va; orow[lane + 64] = vb;
    ushort* brow = outb + (size_t)row * DD;
    brow[lane] = bf16u(va); brow[lane + 64] = bf16u(vb);
}

// ---------------- bf16 MFMA GEMM: C[M,N] (+)= A[M,K](lda) @ W[N,K]^T ----------------
// 128x128 tile, BK=32, 4 waves (2x2 of 64x64), XOR-swizzled 16B chunks in LDS.
__global__ __launch_bounds__(256, 2) void gemm_bf16_kernel(const ushort* __restrict__ A, int lda,
        const ushort* __restrict__ W, float* __restrict__ C, int ldc, int K, int addC) {
    __shared__ ushort As[128 * 32];
    __shared__ ushort Bs[128 * 32];
    int m0 = blockIdx.x * 128;
    int n0 = blockIdx.y * 128;
    int tid = threadIdx.x;
    int wv = tid >> 6, l = tid & 63;
    int lr = l & 15, lg = l >> 4, g4 = lg * 4;
    int wr = wv >> 1, wc = wv & 1;
    int sr = tid >> 1;                  // staging row 0..127
    int sc = (tid & 1) * 2;             // staging chunk base {0,2}

    f32x4 acc[4][4] = {};
    for (int k0 = 0; k0 < K; k0 += 32) {
        __syncthreads();
        #pragma unroll
        for (int u = 0; u < 2; ++u) {
            int c = sc + u;
            uint4 av = *(const uint4*)(A + (size_t)(m0 + sr) * lda + k0 + c * 8);
            *(uint4*)(As + sr * 32 + ((c ^ (sr & 3)) * 8)) = av;
            uint4 wv4 = *(const uint4*)(W + (size_t)(n0 + sr) * K + k0 + c * 8);
            *(uint4*)(Bs + sr * 32 + ((c ^ (sr & 3)) * 8)) = wv4;
        }
        __syncthreads();
        short8 af[4], bf[4];
        #pragma unroll
        for (int fm = 0; fm < 4; ++fm) {
            int row = wr * 64 + fm * 16 + lr;
            af[fm] = *(const short8*)(As + row * 32 + ((lg ^ (row & 3)) * 8));
        }
        #pragma unroll
        for (int fn = 0; fn < 4; ++fn) {
            int row = wc * 64 + fn * 16 + lr;
            bf[fn] = *(const short8*)(Bs + row * 32 + ((lg ^ (row & 3)) * 8));
        }
        #pragma unroll
        for (int fm = 0; fm < 4; ++fm)
            #pragma unroll
            for (int fn = 0; fn < 4; ++fn)
                acc[fm][fn] = __builtin_amdgcn_mfma_f32_16x16x32_bf16(af[fm], bf[fn], acc[fm][fn], 0, 0, 0);
    }
    #pragma unroll
    for (int fm = 0; fm < 4; ++fm) {
        #pragma unroll
        for (int fn = 0; fn < 4; ++fn) {
            #pragma unroll
            for (int r = 0; r < 4; ++r) {
                size_t idx = (size_t)(m0 + wr * 64 + fm * 16 + g4 + r) * ldc + n0 + wc * 64 + fn * 16 + lr;
                if (addC) C[idx] += acc[fm][fn][r]; else C[idx] = acc[fm][fn][r];
            }
        }
    }
}

// ---------------- depthwise causal conv (K=4) + silu (fp32 out + optional bf16 out) ----------------
__global__ __launch_bounds__(256) void conv_silu_kernel(const float* __restrict__ x, int ldx, int C,
        const float* __restrict__ w, const float* __restrict__ bias,
        float* __restrict__ out, int ldo, ushort* __restrict__ outb, int total) {
    int i = blockIdx.x * 256 + threadIdx.x;
    if (i >= total) return;
    int c = i % C;
    size_t row = (size_t)(i / C);
    int s = (int)(row & (SS - 1));
    float acc = bias[c];
    #pragma unroll
    for (int j = 0; j < 4; ++j) {
        int ss = s - 3 + j;
        if (ss >= 0) acc += x[(row + (size_t)(ss - s)) * ldx + c] * w[c * 4 + j];
    }
    float val = siluf_(acc);
    out[row * ldo + c] = val;
    if (outb) outb[row * ldo + c] = bf16u(val);
}

// ---------------- mLSTM block-diagonal q,k,v (8x8 blocks) + bf16 per-head copies ----------------
__global__ __launch_bounds__(256) void mqkv_kernel(const float* __restrict__ xca,
        const float* __restrict__ xz, const float* __restrict__ qw,
        const float* __restrict__ kw, const float* __restrict__ vw,
        float* __restrict__ q, float* __restrict__ k, float* __restrict__ v,
        ushort* __restrict__ qb16, ushort* __restrict__ kb16, int total) {
    int i = blockIdx.x * 256 + threadIdx.x;
    if (i >= total) return;
    int c = i & 255;
    size_t row = (size_t)(i >> 8);
    int nb = c >> 3, e = c & 7;
    const float* xc8 = xca + row * 256 + nb * 8;
    const float* xi8 = xz + row * 512 + nb * 8;
    const float* qw8 = qw + (size_t)(nb * 8 + e) * 8;
    const float* kw8 = kw + (size_t)(nb * 8 + e) * 8;
    const float* vw8 = vw + (size_t)(nb * 8 + e) * 8;
    float aq = 0.f, ak = 0.f, av = 0.f;
    #pragma unroll
    for (int t = 0; t < 8; ++t) {
        float xcv = xc8[t], xiv = xi8[t];
        aq += xcv * qw8[t];
        ak += xcv * kw8[t];
        av += xiv * vw8[t];
    }
    q[i] = aq; k[i] = ak; v[i] = av;
    // bf16 per-head layout [bh][s][64] for the MFMA core
    int h2 = c >> 6, dd = c & 63;
    size_t be = ((((row >> 8) << 2) + h2) * 256 + (row & 255)) * 64 + dd;
    qb16[be] = bf16u(aq);
    kb16[be] = bf16u(ak);
}

// ---------------- mLSTM input/forget gate projections (dot-768 per (row,h)) ----------------
__global__ __launch_bounds__(256) void mgate_kernel(const float* __restrict__ q,
        const float* __restrict__ k, const float* __restrict__ v,
        const float* __restrict__ igw, const float* __restrict__ igb,
        const float* __restrict__ fgw, const float* __restrict__ fgb,
        float* __restrict__ ip, float* __restrict__ fp) {
    int row = blockIdx.x;
    int t = threadIdx.x;
    float qv = q[(size_t)row * 256 + t];
    float kv = k[(size_t)row * 256 + t];
    float vv = v[(size_t)row * 256 + t];
    float pi[4], pf[4];
    #pragma unroll
    for (int hh = 0; hh < 4; ++hh) {
        const float* wi = igw + hh * 768;
        const float* wf = fgw + hh * 768;
        pi[hh] = qv * wi[t] + kv * wi[256 + t] + vv * wi[512 + t];
        pf[hh] = qv * wf[t] + kv * wf[256 + t] + vv * wf[512 + t];
    }
    #pragma unroll
    for (int hh = 0; hh < 4; ++hh) {
        #pragma unroll
        for (int o = 32; o; o >>= 1) {
            pi[hh] += __shfl_xor(pi[hh], o);
            pf[hh] += __shfl_xor(pf[hh], o);
        }
    }
    __shared__ float red[2][4][4];
    int wave = t >> 6, lane = t & 63;
    if (lane == 0) {
        #pragma unroll
        for (int hh = 0; hh < 4; ++hh) { red[0][wave][hh] = pi[hh]; red[1][wave][hh] = pf[hh]; }
    }
    __syncthreads();
    if (t < 8) {
        int g = t >> 2, hh = t & 3;
        float s = red[g][0][hh] + red[g][1][hh] + red[g][2][hh] + red[g][3][hh];
        int b = row >> 8, sidx = row & 255;
        size_t oidx = (size_t)(b * NH + hh) * SS + sidx;
        if (g == 0) ip[oidx] = s + igb[hh];
        else        fp[oidx] = s + fgb[hh];
    }
}

// ---------------- mLSTM decay prefix scan: L (cum log-sigmoid), E = ip - L, PM = prefix-max(E) ----------------
__global__ __launch_bounds__(64) void mprep_kernel(const float* __restrict__ ip,
        const float* __restrict__ fp, float* __restrict__ L,
        float* __restrict__ E, float* __restrict__ PM) {
    int bh = blockIdx.x;
    int lane = threadIdx.x;
    __shared__ float sfp[SS], sip[SS], sL[SS], sE[SS], sPM[SS];
    for (int u = lane; u < SS; u += 64) {
        sfp[u] = fp[(size_t)bh * SS + u];
        sip[u] = ip[(size_t)bh * SS + u];
    }
    __syncthreads();
    if (lane == 0) {
        float run = 0.f, pm = -INFINITY;
        for (int j = 0; j < SS; ++j) {
            run += logsigf_(sfp[j]);
            float e = sip[j] - run;
            pm = fmaxf(pm, e);
            sL[j] = run; sE[j] = e; sPM[j] = pm;
        }
    }
    __syncthreads();
    for (int u = lane; u < SS; u += 64) {
        L[(size_t)bh * SS + u] = sL[u];
        E[(size_t)bh * SS + u] = sE[u];
        PM[(size_t)bh * SS + u] = sPM[u];
    }
}

// ---------------- V transpose to [bh][64][256] bf16 ----------------
__global__ __launch_bounds__(256) void vtrans_kernel(const float* __restrict__ v,
        ushort* __restrict__ vt) {
    int blk = blockIdx.x;
    int st = blk & 3, bh = blk >> 2;
    int b = bh >> 2, h = bh & 3;
    int tid = threadIdx.x;
    __shared__ float tile[64][65];
    int s0 = st * 64;
    #pragma unroll
    for (int u = 0; u < 16; ++u) {
        int idx = u * 256 + tid;
        int sl = idx >> 6, dl = idx & 63;
        tile[sl][dl] = v[((size_t)(b * 256 + s0 + sl)) * 256 + h * 64 + dl];
    }
    __syncthreads();
    #pragma unroll
    for (int u = 0; u < 16; ++u) {
        int idx = u * 256 + tid;
        int dl = idx >> 6, sl = idx & 63;
        vt[((size_t)bh * 64 + dl) * 256 + s0 + sl] = bf16u(tile[sl][dl]);
    }
}

// ---------------- mLSTM parallel core via MFMA ----------------
__global__ __launch_bounds__(256, 2) void mlstm_mfma_kernel(
        const ushort* __restrict__ qb, const ushort* __restrict__ kb,
        const ushort* __restrict__ vt, const float* __restrict__ Lg,
        const float* __restrict__ Eg, const float* __restrict__ PMg,
        float* __restrict__ hmout) {
    int bh = blockIdx.x;
    int b = bh >> 2, h = bh & 3;
    int tid = threadIdx.x;
    int wv = tid >> 6, l = tid & 63;
    int lr = l & 15, lg = l >> 4, g4 = lg * 4;

    __shared__ ushort Kb[16384];     // 32 KB
    __shared__ ushort Vt[16384];     // 32 KB
    __shared__ ushort Pl[4 * 640];   // per-wave 16x40 bf16
    __shared__ float sE[SS], sPM[SS], sL[SS];

    const size_t gb16 = (size_t)bh * 16384;
    #pragma unroll
    for (int p2 = 0; p2 < 8; ++p2) {
        int id = p2 * 256 + tid;
        int r = id >> 3, c = id & 7;
        uint4 kval = *(const uint4*)(kb + gb16 + r * 64 + c * 8);
        *(uint4*)(Kb + r * 64 + ((c ^ (r & 7)) * 8)) = kval;
        int d = id >> 5, c2 = id & 31;
        uint4 vval = *(const uint4*)(vt + gb16 + d * 256 + c2 * 8);
        *(uint4*)(Vt + d * 256 + ((c2 ^ (d & 7)) * 8)) = vval;
    }
    sE[tid]  = Eg[(size_t)bh * SS + tid];
    sPM[tid] = PMg[(size_t)bh * SS + tid];
    sL[tid]  = Lg[(size_t)bh * SS + tid];
    __syncthreads();

    f32x4 O[4][4] = {};
    float csum[4][4] = {};
    const int pmap[4] = {wv, 7 - wv, 8 + wv, 15 - wv};
    ushort* Pw = Pl + wv * 640;
    size_t obase = (size_t)b * SS * 512 + h * 64;

    #pragma unroll
    for (int rf = 0; rf < 4; ++rf) {
        int p = pmap[rf];
        int r0 = p * 16;
        short8 qf0 = *(const short8*)(qb + gb16 + (r0 + lr) * 64 + lg * 8);
        short8 qf1 = *(const short8*)(qb + gb16 + (r0 + lr) * 64 + 32 + lg * 8);
        float pmv[4], lv[4];
        #pragma unroll
        for (int r = 0; r < 4; ++r) { pmv[r] = sPM[r0 + g4 + r]; lv[r] = sL[r0 + g4 + r]; }
        int jtmax = r0 >> 5;
        #pragma unroll 1
        for (int jt = 0; jt <= jtmax; ++jt) {
            int jb = jt * 32;
            f32x4 s0 = {0.f, 0.f, 0.f, 0.f}, s1 = {0.f, 0.f, 0.f, 0.f};
            {
                int j = jb + lr;
                int sw = j & 7;
                short8 k00 = *(const short8*)(Kb + j * 64 + ((lg)     ^ sw) * 8);
                short8 k01 = *(const short8*)(Kb + j * 64 + ((4 + lg) ^ sw) * 8);
                int j2 = jb + 16 + lr;
                int sw2 = j2 & 7;
                short8 k10 = *(const short8*)(Kb + j2 * 64 + ((lg)     ^ sw2) * 8);
                short8 k11 = *(const short8*)(Kb + j2 * 64 + ((4 + lg) ^ sw2) * 8);
                s0 = __builtin_amdgcn_mfma_f32_16x16x32_bf16(qf0, k00, s0, 0, 0, 0);
                s0 = __builtin_amdgcn_mfma_f32_16x16x32_bf16(qf1, k01, s0, 0, 0, 0);
                s1 = __builtin_amdgcn_mfma_f32_16x16x32_bf16(qf0, k10, s1, 0, 0, 0);
                s1 = __builtin_amdgcn_mfma_f32_16x16x32_bf16(qf1, k11, s1, 0, 0, 0);
            }
            float e0 = sE[jb + lr], e1 = sE[jb + 16 + lr];
            int j0 = jb + lr, j1 = jb + 16 + lr;
            #pragma unroll
            for (int r = 0; r < 4; ++r) {
                int i = r0 + g4 + r;
                float sc0 = (j0 <= i) ? s0[r] * 0.125f * __expf(e0 - pmv[r]) : 0.f;
                float sc1 = (j1 <= i) ? s1[r] * 0.125f * __expf(e1 - pmv[r]) : 0.f;
                csum[rf][r] += sc0 + sc1;
                Pw[(g4 + r) * 40 + lr] = bf16u(sc0);
                Pw[(g4 + r) * 40 + 16 + lr] = bf16u(sc1);
            }
            WAVE_SYNC();
            short8 pf = *(const short8*)(Pw + lr * 40 + lg * 8);
            #pragma unroll
            for (int dc = 0; dc < 4; ++dc) {
                int d = dc * 16 + lr;
                int chunk = (jt * 4 + lg) ^ (d & 7);
                short8 vf = *(const short8*)(Vt + d * 256 + chunk * 8);
                O[rf][dc] = __builtin_amdgcn_mfma_f32_16x16x32_bf16(pf, vf, O[rf][dc], 0, 0, 0);
            }
        }
        float rinv[4];
        #pragma unroll
        for (int r = 0; r < 4; ++r) {
            float cs = csum[rf][r];
            cs += __shfl_xor(cs, 1); cs += __shfl_xor(cs, 2);
            cs += __shfl_xor(cs, 4); cs += __shfl_xor(cs, 8);
            float nrm = fmaxf(fabsf(cs), __expf(-(lv[r] + pmv[r]))) + 1e-6f;
            rinv[r] = 1.f / nrm;
        }
        #pragma unroll
        for (int dc = 0; dc < 4; ++dc)
            #pragma unroll
            for (int r = 0; r < 4; ++r)
                hmout[obase + (size_t)(r0 + g4 + r) * 512 + dc * 16 + lr] = O[rf][dc][r] * rinv[r];
    }
}

// ---------------- mLSTM post: group-LN(64) + skip + silu(z) -> bf16 [NR][256] ----------------
__global__ __launch_bounds__(256) void mpost_kernel(const float* __restrict__ xzbuf,
        const float* __restrict__ xca, const float* __restrict__ onw,
        const float* __restrict__ skip, ushort* __restrict__ outb) {
    int row = blockIdx.x;
    int t = threadIdx.x;
    size_t base = (size_t)row * 512;
    float hm = xzbuf[base + t];
    float s1 = hm, s2 = hm * hm;
    #pragma unroll
    for (int o = 32; o; o >>= 1) { s1 += __shfl_xor(s1, o); s2 += __shfl_xor(s2, o); }
    float mu = s1 * (1.f / 64.f);
    float var = s2 * (1.f / 64.f) - mu * mu;
    float xnv = (hm - mu) * rsqrtf(var + 1e-5f) * onw[t];
    float z = xzbuf[base + 256 + t];
    float val = (xnv + skip[t] * xca[(size_t)row * 256 + t]) * siluf_(z);
    outb[(size_t)row * 256 + t] = bf16u(val);
}

// ---------------- sLSTM sequential scan: one wave per (b,h), all-register, VALU cross-lane ----------------
// gif[row][256]: col h*64+l = x-gate (l<32: i ch l, l>=32: f ch l-32); gzo likewise (z,o).
// rec_w (NH,32,128): lane l holds cols l and 64+l of head h's matrix in registers.
// __launch_bounds__(64, 1): allow max VGPRs so w01[32] (64 VGPRs) stays register-resident —
// R4-R7 allocator kept VGPR_Count ~72-80, reloading w01 from L2 every step (~1810 cyc/step).
// Only 2 waves/CU are ever resident (512 blocks / 256 CUs), so there is no occupancy cost.
__global__ __launch_bounds__(64, 1) void slstm_scan_kernel(const float* __restrict__ gif,
        const float* __restrict__ gzo, const float* __restrict__ rec_w,
        const float* __restrict__ bias, const float* __restrict__ gnw,
        float* __restrict__ hbuf) {
    int bh = blockIdx.x;
    int b = bh >> 2, h = bh & 3;
    int l = threadIdx.x;
    int c = l & 31;
    bool lo = (l < 32);
    f32x2 w01[32];   // .x -> col l (raw0), .y -> col 64+l (raw1)
    const float* wp = rec_w + (size_t)h * 4096 + l;
    #pragma unroll
    for (int d = 0; d < 32; ++d) {
        w01[d].x = wp[d * 128];
        w01[d].y = wp[d * 128 + 64];
    }
    float b0 = bias[h * 128 + l];
    float b1 = bias[h * 128 + 64 + l];
    float gw = gnw[h * 32 + c];
    float cst = 0.f, nst = 0.f, mst = 0.f, hreg = 0.f;
    size_t gb = (size_t)b * SS * 256 + h * 64 + l;
    size_t hb = (size_t)b * SS * 128 + h * 32 + c;
    float pg0[8], pg1[8], ph[8];
    #pragma unroll
    for (int u = 0; u < 8; ++u) {
        pg0[u] = gif[gb + (size_t)u * 256];
        pg1[u] = gzo[gb + (size_t)u * 256];
        ph[u]  = hbuf[hb + (size_t)u * 128];
    }
    for (int s = 0; s < SS; s += 8) {
        #pragma unroll
        for (int u = 0; u < 8; ++u) {
            // recurrent matvec: readlane broadcast (VALU), f32x2 packed accum, ILP-4
            f32x2 a0 = {0.f, 0.f}, a1 = {0.f, 0.f}, a2 = {0.f, 0.f}, a3 = {0.f, 0.f};
            #pragma unroll
            for (int d = 0; d < 32; d += 4) {
                float h0 = rdlane(hreg, d);
                float h1 = rdlane(hreg, d + 1);
                float h2 = rdlane(hreg, d + 2);
                float h3 = rdlane(hreg, d + 3);
                a0 += w01[d] * h0;
                a1 += w01[d + 1] * h1;
                a2 += w01[d + 2] * h2;
                a3 += w01[d + 3] * h3;
            }
            f32x2 sacc = (a0 + a1) + (a2 + a3);
            float raw0 = pg0[u] + sacc.x + b0;
            float raw1 = pg1[u] + sacc.y + b1;
            float hcur = ph[u];
            int s8 = s + 8 + u;
            if (s8 < SS) {
                pg0[u] = gif[gb + (size_t)s8 * 256];
                pg1[u] = gzo[gb + (size_t)s8 * 256];
                ph[u]  = hbuf[hb + (size_t)s8 * 128];
            }
            // half-swap via permlane32_swap (VALU)
            i32x2 r0p = __builtin_amdgcn_permlane32_swap(__float_as_int(raw0), __float_as_int(raw0), false, false);
            i32x2 r1p = __builtin_amdgcn_permlane32_swap(__float_as_int(raw1), __float_as_int(raw1), false, false);
            float q0 = __int_as_float(lo ? r0p.y : r0p.x);
            float q1 = __int_as_float(lo ? r1p.y : r1p.x);
            float iraw = lo ? raw0 : q0;
            float zraw = lo ? raw1 : q1;
            float fraw = lo ? q0 : raw0;
            float oraw = lo ? q1 : raw1;
            float lfm = mst + fminf(fraw, 0.f) - __logf(1.f + __expf(-fabsf(fraw)));
            float mnew = fmaxf(iraw, lfm);
            float ig = __expf(iraw - mnew);
            float fg = __expf(lfm - mnew);
            float e2z = __expf(2.f * zraw);
            float tz = 1.f - 2.f * __builtin_amdgcn_rcpf(e2z + 1.f);
            cst = fg * cst + ig * tz;
            nst = fg * nst + ig;
            mst = mnew;
            float sg = __builtin_amdgcn_rcpf(1.f + __expf(-oraw));
            float hv = sg * cst * __builtin_amdgcn_rcpf(nst);
            hreg = hv;
            // fused group-LN(32) + residual; DPP tree sum over all 64 lanes (= 2x 32-sum)
            float s1 = hv, s2 = hv * hv;
            s1 = DPPADD(s1, 0x111); s2 = DPPADD(s2, 0x111);   // row_shr:1
            s1 = DPPADD(s1, 0x112); s2 = DPPADD(s2, 0x112);   // row_shr:2
            s1 = DPPADD(s1, 0x114); s2 = DPPADD(s2, 0x114);   // row_shr:4
            s1 = DPPADD(s1, 0x118); s2 = DPPADD(s2, 0x118);   // row_shr:8
            s1 = DPPADD(s1, 0x142); s2 = DPPADD(s2, 0x142);   // row_bcast:15
            s1 = DPPADD(s1, 0x143); s2 = DPPADD(s2, 0x143);   // row_bcast:31
            float mu = rdlane(s1, 63) * (1.f / 64.f);
            float var = rdlane(s2, 63) * (1.f / 64.f) - mu * mu;
            float outv = (hv - mu) * rsqrtf(var + 1e-5f) * gw;
            if (lo) hbuf[hb + (size_t)(s + u) * 128] = hcur + outv;
        }
    }
}

// ---------------- gated-GELU (exact erf) -> bf16 ----------------
__global__ __launch_bounds__(256) void geluglu_kernel(const float* __restrict__ xzbuf,
        ushort* __restrict__ gg, int total) {
    int i = blockIdx.x * 256 + threadIdx.x;
    if (i >= total) return;
    int c = i & 255;
    size_t row = (size_t)(i >> 8);
    float g = xzbuf[row * 512 + c];
    float u = xzbuf[row * 512 + 256 + c];
    float ge = 0.5f * g * (1.f + erff(g * 0.70710678118654752f));
    gg[i] = bf16u(ge * u);
}

extern "C" void kernel_launch(void* const* d_in, const int* in_sizes, int n_in,
                              void* d_out, int out_size, void* d_ws, size_t ws_size,
                              hipStream_t stream) {
    const int*   x        = (const int*)d_in[0];
    const float* emb      = (const float*)d_in[1];
    const float* m_ln_w   = (const float*)d_in[2];
    const float* m_up_w   = (const float*)d_in[3];
    const float* m_conv_w = (const float*)d_in[4];
    const float* m_conv_b = (const float*)d_in[5];
    const float* m_q_w    = (const float*)d_in[6];
    const float* m_k_w    = (const float*)d_in[7];
    const float* m_v_w    = (const float*)d_in[8];
    const float* m_ig_w   = (const float*)d_in[9];
    const float* m_ig_b   = (const float*)d_in[10];
    const float* m_fg_w   = (const float*)d_in[11];
    const float* m_fg_b   = (const float*)d_in[12];
    const float* m_on_w   = (const float*)d_in[13];
    const float* m_skip   = (const float*)d_in[14];
    const float* m_down_w = (const float*)d_in[15];
    const float* s_ln1_w  = (const float*)d_in[16];
    const float* s_conv_w = (const float*)d_in[17];
    const float* s_conv_b = (const float*)d_in[18];
    const float* s_ig_w   = (const float*)d_in[19];
    const float* s_fg_w   = (const float*)d_in[20];
    const float* s_zg_w   = (const float*)d_in[21];
    const float* s_og_w   = (const float*)d_in[22];
    const float* s_rec_w  = (const float*)d_in[23];
    const float* s_bias   = (const float*)d_in[24];
    const float* s_gn_w   = (const float*)d_in[25];
    const float* s_ln2_w  = (const float*)d_in[26];
    const float* s_ff_up_w   = (const float*)d_in[27];
    const float* s_ff_down_w = (const float*)d_in[28];
    const float* post_norm_w = (const float*)d_in[29];
    float* out = (float*)d_out;

    float* ws = (float*)d_ws;
    const size_t NR = NROWS;
    float* h   = ws;                   // NR*128
    float* xn  = h   + NR * 128;       // NR*128 fp32 (later qb16 alias)
    float* xz  = xn  + NR * 128;       // NR*512
    float* xca = xz  + NR * 512;       // NR*256
    float* q   = xca + NR * 256;       // NR*256 (q fp32; later mpostb bf16; later gif fp32)
    float* k   = q   + NR * 256;       // NR*256 (k fp32; later vtb bf16; later gzo fp32)
    float* v   = k   + NR * 256;       // NR*256 (v fp32)
    float* gip = v   + NR * 256;       // 512*256
    float* gfp = gip + 512 * 256;
    float* gL  = gfp + 512 * 256;
    float* gE  = gL  + 512 * 256;
    float* gPM = gE  + 512 * 256;
    float* extra = gPM + 512 * 256;
    // bf16 regions
    ushort* xnb   = (ushort*)extra;                    // NR*128 bf16
    ushort* upb   = (ushort*)(extra + NR * 64);        // 512*128
    ushort* downb = upb + 512 * 128;                   // 128*256
    ushort* ffupb = downb + 128 * 256;                 // 2*512*128
    ushort* ffdownb = ffupb + 2 * 512 * 128;           // 2*128*256
    ushort* sgwb  = ffdownb + 2 * 128 * 256;           // 2*2*256*128
    // aliases (regions dead at time of use)
    ushort* qb16   = (ushort*)xn;     // NR*256 bf16
    ushort* kb16   = (ushort*)out;    // NR*256 bf16
    ushort* vtb    = (ushort*)k;      // NR*256 bf16
    ushort* mpostb = (ushort*)q;      // NR*256 bf16
    ushort* xcb    = (ushort*)(xca + NR * 128);   // NR*128 bf16
    ushort* ggb    = (ushort*)xca;    // NR*256 bf16
    float* gif = q;                   // NR*256 fp32
    float* gzo = k;                   // NR*256 fp32

    // ---- weight conversions ----
    tobf16_kernel<<<(512 * 128 + 255) / 256, 256, 0, stream>>>(m_up_w, upb, 512 * 128);
    tobf16_kernel<<<(128 * 256 + 255) / 256, 256, 0, stream>>>(m_down_w, downb, 128 * 256);
    tobf16_kernel<<<(2 * 512 * 128 + 255) / 256, 256, 0, stream>>>(s_ff_up_w, ffupb, 2 * 512 * 128);
    tobf16_kernel<<<(2 * 128 * 256 + 255) / 256, 256, 0, stream>>>(s_ff_down_w, ffdownb, 2 * 128 * 256);
    densify_kernel<<<(2 * 2 * 256 * 128) / 256, 256, 0, stream>>>(s_ig_w, s_fg_w, s_zg_w, s_og_w, sgwb);

    // ---- embedding + pre-LN ----
    embed_kernel<<<(NR * 128) / 256, 256, 0, stream>>>(x, emb, h, NR * 128);
    ln128_kernel<<<NR, 64, 0, stream>>>(h, m_ln_w, xn, xnb);
    // ---- mLSTM up-projection (bf16 MFMA) ----
    gemm_bf16_kernel<<<dim3(NR / 128, 4), 256, 0, stream>>>(xnb, 128, upb, xz, 512, 128, 0);
    // ---- causal conv + silu ----
    conv_silu_kernel<<<(NR * 256) / 256, 256, 0, stream>>>(xz, 512, 256, m_conv_w, m_conv_b, xca, 256, nullptr, NR * 256);
    // ---- block-diag q,k,v (+ bf16 copies) ----
    mqkv_kernel<<<(NR * 256) / 256, 256, 0, stream>>>(xca, xz, m_q_w, m_k_w, m_v_w, q, k, v, qb16, kb16, NR * 256);
    // ---- i/f gate projections ----
    mgate_kernel<<<NR, 256, 0, stream>>>(q, k, v, m_ig_w, m_ig_b, m_fg_w, m_fg_b, gip, gfp);
    // ---- decay prefix scan ----
    mprep_kernel<<<BB * NH, 64, 0, stream>>>(gip, gfp, gL, gE, gPM);
    // ---- V transpose to bf16 (into dead k fp32 space) ----
    vtrans_kernel<<<BB * NH * 4, 256, 0, stream>>>(v, vtb);
    // ---- mLSTM parallel core via MFMA (hm -> x_in half of xz) ----
    mlstm_mfma_kernel<<<BB * NH, 256, 0, stream>>>(qb16, kb16, vtb, gL, gE, gPM, xz);
    // ---- post: group-LN + skip + silu(z) -> bf16 (q region now dead) ----
    mpost_kernel<<<NR, 256, 0, stream>>>(xz, xca, m_on_w, m_skip, mpostb);
    // ---- down-projection + residual (bf16 MFMA, accumulate) ----
    gemm_bf16_kernel<<<dim3(NR / 128, 1), 256, 0, stream>>>(mpostb, 256, downb, h, 128, 256, 1);

    // ---- two sLSTM blocks ----
    for (int i2 = 0; i2 < 2; ++i2) {
        ln128_kernel<<<NR, 64, 0, stream>>>(h, s_ln1_w + i2 * 128, xn, xnb);
        conv_silu_kernel<<<(NR * 128) / 256, 256, 0, stream>>>(xn, 128, 128, s_conv_w + i2 * 128 * 4, s_conv_b + i2 * 128, xca, 128, xcb, NR * 128);
        // gates via dense bf16 GEMMs: [i|f]-perm = xc @ Wif'^T, [z|o]-perm = xn @ Wzo'^T
        gemm_bf16_kernel<<<dim3(NR / 128, 2), 256, 0, stream>>>(xcb, 128, sgwb + (size_t)(i2 * 2 + 0) * 256 * 128, gif, 256, 128, 0);
        gemm_bf16_kernel<<<dim3(NR / 128, 2), 256, 0, stream>>>(xnb, 128, sgwb + (size_t)(i2 * 2 + 1) * 256 * 128, gzo, 256, 128, 0);
        // scan with fused group-LN + residual into h
        slstm_scan_kernel<<<BB * NH, 64, 0, stream>>>(gif, gzo,
                s_rec_w + i2 * 4 * 32 * 128, s_bias + i2 * 4 * 128, s_gn_w + i2 * 128, h);
        ln128_kernel<<<NR, 64, 0, stream>>>(h, s_ln2_w + i2 * 128, xn, xnb);
        gemm_bf16_kernel<<<dim3(NR / 128, 4), 256, 0, stream>>>(xnb, 128, ffupb + (size_t)i2 * 512 * 128, xz, 512, 128, 0);
        geluglu_kernel<<<(NR * 256) / 256, 256, 0, stream>>>(xz, ggb, NR * 256);
        gemm_bf16_kernel<<<dim3(NR / 128, 1), 256, 0, stream>>>(ggb, 256, ffdownb + (size_t)i2 * 128 * 256, h, 128, 256, 1);
    }
    // ---- final LN -> out ----
    ln128_kernel<<<NR, 64, 0, stream>>>(h, post_norm_w, out, xnb);
}